// Round 1
// baseline (109.329 us; speedup 1.0000x reference)
//
#include <hip/hip_runtime.h>
#include <math.h>

// Problem: B=512, N=64, D=3, H=128.
// out[b,i,:] = sum_{j != i} g(dist_ij) * (pos[b,i,:] - pos[b,j,:])
// where g(d) = (MLP(features(d)) + b3) / max(d, 0.01).
// g depends ONLY on the scalar dist -> tabulate g on a dense grid, lerp.

#define TMAX 131072      // max table entries (512 KiB of ws)
#define DMAX 16.0f       // table covers d in [0, 16); data max-dist ~ 11

__device__ __forceinline__ float fast_tanh(float x) {
    // 1 - 2/(e^{2x}+1); exp overflow -> inf -> 1.0, underflow -> 0 -> -1.0 (both correct)
    float e = __expf(2.0f * x);
    return 1.0f - 2.0f / (e + 1.0f);
}

__global__ __launch_bounds__(256) void build_table(
    const float* __restrict__ W1, const float* __restrict__ b1,
    const float* __restrict__ W2, const float* __restrict__ b2,
    const float* __restrict__ W3, const float* __restrict__ b3,
    float* __restrict__ tab, int tsize, float delta) {
    __shared__ float sW1[6 * 128];
    __shared__ float sb1[128], sb2[128], sW3[128];
    for (int idx = threadIdx.x; idx < 768; idx += 256) sW1[idx] = W1[idx];
    if (threadIdx.x < 128) {
        sb1[threadIdx.x] = b1[threadIdx.x];
        sb2[threadIdx.x] = b2[threadIdx.x];
        sW3[threadIdx.x] = W3[threadIdx.x];
    }
    __syncthreads();

    int t = blockIdx.x * 256 + threadIdx.x;
    if (t >= tsize) return;
    float d = (float)t * delta;

    float inv_r = 1.0f / fmaxf(d, 0.5f);
    float inv2  = inv_r * inv_r;
    float inv6  = inv2 * inv2 * inv2;
    float inv12 = inv6 * inv6;
    float f0 = d, f1 = inv_r, f2 = inv6, f3 = inv12, f4 = inv6 * inv_r, f5 = inv12 * inv_r;

    // Layer 1: feat[6] @ W1[6,128] + b1 -> tanh. h1 kept in registers (static idx).
    float h1[128];
#pragma unroll
    for (int h = 0; h < 128; ++h) {
        float a = sb1[h];
        a = fmaf(f0, sW1[0 * 128 + h], a);
        a = fmaf(f1, sW1[1 * 128 + h], a);
        a = fmaf(f2, sW1[2 * 128 + h], a);
        a = fmaf(f3, sW1[3 * 128 + h], a);
        a = fmaf(f4, sW1[4 * 128 + h], a);
        a = fmaf(f5, sW1[5 * 128 + h], a);
        h1[h] = fast_tanh(a);
    }

    // Layer 2 + 3 fused: h2 = tanh(h1 @ W2 + b2); mag = h2 @ W3 + b3.
    // W2 address is wave-uniform (no lane dependence) -> broadcast/scalar loads.
    float mag = b3[0];
    for (int n = 0; n < 128; n += 4) {
        float a0 = sb2[n + 0], a1 = sb2[n + 1], a2 = sb2[n + 2], a3 = sb2[n + 3];
#pragma unroll
        for (int h = 0; h < 128; ++h) {
            const float4 w = *reinterpret_cast<const float4*>(W2 + h * 128 + n);
            a0 = fmaf(h1[h], w.x, a0);
            a1 = fmaf(h1[h], w.y, a1);
            a2 = fmaf(h1[h], w.z, a2);
            a3 = fmaf(h1[h], w.w, a3);
        }
        mag = fmaf(fast_tanh(a0), sW3[n + 0], mag);
        mag = fmaf(fast_tanh(a1), sW3[n + 1], mag);
        mag = fmaf(fast_tanh(a2), sW3[n + 2], mag);
        mag = fmaf(fast_tanh(a3), sW3[n + 3], mag);
    }

    tab[t] = mag / fmaxf(d, 0.01f);
}

// One wave per (b, i); lane = j. 4 i's per 256-thread block.
__global__ __launch_bounds__(256) void force_kernel(
    const float* __restrict__ pos, const float* __restrict__ tab,
    float* __restrict__ out, int tsize, float inv_delta) {
    __shared__ float sp[192];
    int b = blockIdx.x >> 4;                 // 512 batches
    int igrp = (blockIdx.x & 15) << 2;       // 16 groups of 4 i's
    for (int idx = threadIdx.x; idx < 192; idx += 256)
        sp[idx] = pos[b * 192 + idx];
    __syncthreads();

    int w = threadIdx.x >> 6;
    int lane = threadIdx.x & 63;
    int i = igrp + w;

    float xi = sp[i * 3 + 0], yi = sp[i * 3 + 1], zi = sp[i * 3 + 2];
    float dx = xi - sp[lane * 3 + 0];
    float dy = yi - sp[lane * 3 + 1];
    float dz = zi - sp[lane * 3 + 2];
    float sq = fmaf(dx, dx, fmaf(dy, dy, dz * dz));
    float dist = sqrtf(sq);

    float tpos = dist * inv_delta;
    int idx0 = (int)tpos;
    idx0 = min(idx0, tsize - 2);
    float fr = tpos - (float)idx0;
    float g0 = tab[idx0], g1 = tab[idx0 + 1];
    float g = fmaf(fr, g1 - g0, g0);
    if (lane == i) g = 0.0f;   // off-diagonal mask

    float fx = g * dx, fy = g * dy, fz = g * dz;
#pragma unroll
    for (int s = 32; s > 0; s >>= 1) {
        fx += __shfl_xor(fx, s);
        fy += __shfl_xor(fy, s);
        fz += __shfl_xor(fz, s);
    }
    if (lane == 0) {
        int o = (b * 64 + i) * 3;
        out[o + 0] = fx;
        out[o + 1] = fy;
        out[o + 2] = fz;
    }
}

extern "C" void kernel_launch(void* const* d_in, const int* in_sizes, int n_in,
                              void* d_out, int out_size, void* d_ws, size_t ws_size,
                              hipStream_t stream) {
    const float* pos = (const float*)d_in[0];
    const float* W1  = (const float*)d_in[1];
    const float* b1  = (const float*)d_in[2];
    const float* W2  = (const float*)d_in[3];
    const float* b2  = (const float*)d_in[4];
    const float* W3  = (const float*)d_in[5];
    const float* b3  = (const float*)d_in[6];
    float* tab = (float*)d_ws;
    float* out = (float*)d_out;

    // size table to workspace (pow2, <= TMAX)
    int tsize = TMAX;
    while ((size_t)tsize * sizeof(float) > ws_size && tsize > 256) tsize >>= 1;
    float delta = DMAX / (float)tsize;
    float inv_delta = (float)tsize / DMAX;

    hipLaunchKernelGGL(build_table, dim3((tsize + 255) / 256), dim3(256), 0, stream,
                       W1, b1, W2, b2, W3, b3, tab, tsize, delta);
    hipLaunchKernelGGL(force_kernel, dim3(512 * 16), dim3(256), 0, stream,
                       pos, tab, out, tsize, inv_delta);
}

// Round 2
// 44.294 us; speedup vs baseline: 2.4683x; 2.4683x over previous
//
#include <hip/hip_runtime.h>
#include <hip/hip_bf16.h>
#include <math.h>

// Problem: B=512, N=64, D=3, H=128.
// out[b,i,:] = sum_{j != i} g(dist_ij) * (pos[b,i,:] - pos[b,j,:])
// where g(d) = (MLP(features(d)) + b3) / max(d, 0.01).
// g depends ONLY on scalar dist -> tabulate g on a dense grid, lerp.
// Table build: layer2 is [tsize,128]@[128,128] -> bf16 MFMA per 64-entry block.

#define TMAX 131072      // max table entries (512 KiB of ws)
#define DMAX 16.0f       // table covers d in [0, 16); data max-dist ~ 11
#define ENTRIES 64       // table entries per block

typedef __attribute__((ext_vector_type(8))) short bf16x8;
typedef __attribute__((ext_vector_type(4))) float f32x4;
typedef __attribute__((ext_vector_type(8))) unsigned short ushort8_t;

__device__ __forceinline__ float fast_tanh(float x) {
    // 1 - 2/(e^{2x}+1); overflow -> 1.0, underflow -> -1.0 (both correct)
    float e = __expf(2.0f * x);
    return 1.0f - 2.0f * __builtin_amdgcn_rcpf(e + 1.0f);
}

__device__ __forceinline__ unsigned short f2bf(float x) {
    __hip_bfloat16 h = __float2bfloat16(x);
    return *reinterpret_cast<unsigned short*>(&h);
}

__global__ __launch_bounds__(256) void build_table(
    const float* __restrict__ W1, const float* __restrict__ b1,
    const float* __restrict__ W2, const float* __restrict__ b2,
    const float* __restrict__ W3, const float* __restrict__ b3,
    float* __restrict__ tab, float delta) {
    __shared__ float sW1[6 * 128];
    __shared__ float sb1[128], sb2[128], sW3[128];
    __shared__ unsigned short sH1[ENTRIES][136];   // [entry][k] bf16, pad->272B rows (16B aligned)
    __shared__ unsigned short sW2T[128][136];      // [n][k] bf16 (W2 transposed)

    const int t = threadIdx.x;

    // ---- stage weights ----
    if (t < 128) { sb1[t] = b1[t]; sb2[t] = b2[t]; sW3[t] = W3[t]; }
    for (int i = t; i < 768; i += 256) sW1[i] = W1[i];

    // W2 [128k][128n] fp32 -> sW2T [n][k] bf16. Thread: k-pair h0,h0+1; 32 cols.
    {
        int h0 = 2 * (t >> 2);
        int n0 = (t & 3) * 32;
        const float* rA = W2 + h0 * 128 + n0;
        const float* rB = rA + 128;
#pragma unroll
        for (int j = 0; j < 8; ++j) {
            float4 wa = *reinterpret_cast<const float4*>(rA + 4 * j);
            float4 wb = *reinterpret_cast<const float4*>(rB + 4 * j);
            ushort2 p0 = make_ushort2(f2bf(wa.x), f2bf(wb.x));
            ushort2 p1 = make_ushort2(f2bf(wa.y), f2bf(wb.y));
            ushort2 p2 = make_ushort2(f2bf(wa.z), f2bf(wb.z));
            ushort2 p3 = make_ushort2(f2bf(wa.w), f2bf(wb.w));
            *reinterpret_cast<ushort2*>(&sW2T[n0 + 4 * j + 0][h0]) = p0;
            *reinterpret_cast<ushort2*>(&sW2T[n0 + 4 * j + 1][h0]) = p1;
            *reinterpret_cast<ushort2*>(&sW2T[n0 + 4 * j + 2][h0]) = p2;
            *reinterpret_cast<ushort2*>(&sW2T[n0 + 4 * j + 3][h0]) = p3;
        }
    }
    __syncthreads();

    // ---- phase 1: h1 = tanh(feat @ W1 + b1), bf16 into sH1 ----
    {
        int e  = t >> 2;          // 0..63
        int c0 = (t & 3) * 32;    // 32 cols per thread
        float d = (float)(blockIdx.x * ENTRIES + e) * delta;
        float inv_r = 1.0f / fmaxf(d, 0.5f);
        float inv2  = inv_r * inv_r;
        float inv6  = inv2 * inv2 * inv2;
        float inv12 = inv6 * inv6;
        float f0 = d, f1 = inv_r, f2 = inv6, f3 = inv12, f4 = inv6 * inv_r, f5 = inv12 * inv_r;
#pragma unroll
        for (int c8 = 0; c8 < 32; c8 += 8) {
            ushort8_t pk;
#pragma unroll
            for (int j = 0; j < 8; ++j) {
                int col = c0 + c8 + j;
                float a = sb1[col];
                a = fmaf(f0, sW1[0 * 128 + col], a);
                a = fmaf(f1, sW1[1 * 128 + col], a);
                a = fmaf(f2, sW1[2 * 128 + col], a);
                a = fmaf(f3, sW1[3 * 128 + col], a);
                a = fmaf(f4, sW1[4 * 128 + col], a);
                a = fmaf(f5, sW1[5 * 128 + col], a);
                pk[j] = f2bf(fast_tanh(a));
            }
            *reinterpret_cast<ushort8_t*>(&sH1[e][c0 + c8]) = pk;
        }
    }
    __syncthreads();

    // ---- phase 2: MFMA layer2 + fused tanh/W3 epilogue ----
    {
        int w  = t >> 6;     // wave 0..3 -> m-tile rows w*16..w*16+15
        int l  = t & 63;
        int lg = l >> 4;     // k-group
        int lr = l & 15;     // A-row / B-col within tile

        bf16x8 afr[4];
#pragma unroll
        for (int kt = 0; kt < 4; ++kt)
            afr[kt] = *reinterpret_cast<const bf16x8*>(&sH1[w * 16 + lr][kt * 32 + lg * 8]);

        float part[4] = {0.f, 0.f, 0.f, 0.f};
        float b3v = b3[0];
#pragma unroll
        for (int nt = 0; nt < 8; ++nt) {
            f32x4 acc = {0.f, 0.f, 0.f, 0.f};
#pragma unroll
            for (int kt = 0; kt < 4; ++kt) {
                bf16x8 bfr = *reinterpret_cast<const bf16x8*>(&sW2T[nt * 16 + lr][kt * 32 + lg * 8]);
                acc = __builtin_amdgcn_mfma_f32_16x16x32_bf16(afr[kt], bfr, acc, 0, 0, 0);
            }
            float b2v = sb2[nt * 16 + lr];
            float w3v = sW3[nt * 16 + lr];
#pragma unroll
            for (int r = 0; r < 4; ++r)
                part[r] = fmaf(fast_tanh(acc[r] + b2v), w3v, part[r]);
        }
        // reduce over n (the 16 lr-lanes within each 16-lane group)
#pragma unroll
        for (int s = 1; s < 16; s <<= 1) {
#pragma unroll
            for (int r = 0; r < 4; ++r) part[r] += __shfl_xor(part[r], s);
        }
        if (lr == 0) {
            int ebase = w * 16 + lg * 4;   // D row = (l>>4)*4 + r
#pragma unroll
            for (int r = 0; r < 4; ++r) {
                int tt = blockIdx.x * ENTRIES + ebase + r;
                float d = (float)tt * delta;
                tab[tt] = (part[r] + b3v) / fmaxf(d, 0.01f);
            }
        }
    }
}

// One wave per (b, i); lane = j. 4 i's per 256-thread block.
__global__ __launch_bounds__(256) void force_kernel(
    const float* __restrict__ pos, const float* __restrict__ tab,
    float* __restrict__ out, int tsize, float inv_delta) {
    __shared__ float sp[192];
    int b = blockIdx.x >> 4;                 // 512 batches
    int igrp = (blockIdx.x & 15) << 2;       // 16 groups of 4 i's
    for (int idx = threadIdx.x; idx < 192; idx += 256)
        sp[idx] = pos[b * 192 + idx];
    __syncthreads();

    int w = threadIdx.x >> 6;
    int lane = threadIdx.x & 63;
    int i = igrp + w;

    float xi = sp[i * 3 + 0], yi = sp[i * 3 + 1], zi = sp[i * 3 + 2];
    float dx = xi - sp[lane * 3 + 0];
    float dy = yi - sp[lane * 3 + 1];
    float dz = zi - sp[lane * 3 + 2];
    float sq = fmaf(dx, dx, fmaf(dy, dy, dz * dz));
    float dist = sqrtf(sq);

    float tpos = dist * inv_delta;
    int idx0 = (int)tpos;
    idx0 = min(idx0, tsize - 2);
    float fr = tpos - (float)idx0;
    float g0 = tab[idx0], g1 = tab[idx0 + 1];
    float g = fmaf(fr, g1 - g0, g0);
    if (lane == i) g = 0.0f;   // off-diagonal mask

    float fx = g * dx, fy = g * dy, fz = g * dz;
#pragma unroll
    for (int s = 32; s > 0; s >>= 1) {
        fx += __shfl_xor(fx, s);
        fy += __shfl_xor(fy, s);
        fz += __shfl_xor(fz, s);
    }
    if (lane == 0) {
        int o = (b * 64 + i) * 3;
        out[o + 0] = fx;
        out[o + 1] = fy;
        out[o + 2] = fz;
    }
}

extern "C" void kernel_launch(void* const* d_in, const int* in_sizes, int n_in,
                              void* d_out, int out_size, void* d_ws, size_t ws_size,
                              hipStream_t stream) {
    const float* pos = (const float*)d_in[0];
    const float* W1  = (const float*)d_in[1];
    const float* b1  = (const float*)d_in[2];
    const float* W2  = (const float*)d_in[3];
    const float* b2  = (const float*)d_in[4];
    const float* W3  = (const float*)d_in[5];
    const float* b3  = (const float*)d_in[6];
    float* tab = (float*)d_ws;
    float* out = (float*)d_out;

    // size table to workspace (pow2, <= TMAX)
    int tsize = TMAX;
    while ((size_t)tsize * sizeof(float) > ws_size && tsize > 256) tsize >>= 1;
    float delta = DMAX / (float)tsize;
    float inv_delta = (float)tsize / DMAX;

    hipLaunchKernelGGL(build_table, dim3(tsize / ENTRIES), dim3(256), 0, stream,
                       W1, b1, W2, b2, W3, b3, tab, delta);
    hipLaunchKernelGGL(force_kernel, dim3(512 * 16), dim3(256), 0, stream,
                       pos, tab, out, tsize, inv_delta);
}

// Round 3
// 39.547 us; speedup vs baseline: 2.7645x; 1.1200x over previous
//
#include <hip/hip_runtime.h>
#include <hip/hip_bf16.h>
#include <math.h>

// Problem: B=512, N=64, D=3, H=128.
// out[b,i,:] = sum_{j != i} g(dist_ij) * (pos[b,i,:] - pos[b,j,:])
// where g(d) = (MLP(features(d)) + b3) / max(d, 0.01).
// g depends ONLY on scalar dist -> tabulate g, lerp.
// Two-resolution table: fine [0,2) x 65536 (tanh-front region needs ~3e-5
// spacing), coarse [0,16) x 16384 (features smooth there).
// Table layer2 is [E,128]@[128,128] -> bf16 MFMA; W2^T pre-converted once.

#define NFINE   65536
#define NCOARSE 16384
#define DFINE   (2.0f / (float)NFINE)
#define DCOARSE (16.0f / (float)NCOARSE)
#define ENTRIES 64

typedef __attribute__((ext_vector_type(8))) short bf16x8;
typedef __attribute__((ext_vector_type(4))) float f32x4;
typedef __attribute__((ext_vector_type(8))) unsigned short ushort8_t;

__device__ __forceinline__ float fast_tanh(float x) {
    float e = __expf(2.0f * x);
    return 1.0f - 2.0f * __builtin_amdgcn_rcpf(e + 1.0f);
}

__device__ __forceinline__ unsigned short f2bf(float x) {
    __hip_bfloat16 h = __float2bfloat16(x);
    return *reinterpret_cast<unsigned short*>(&h);
}

// One-time: W2 [128h][128n] fp32 -> W2T [n][h] bf16, rows padded to 136.
__global__ __launch_bounds__(256) void prep_w2(
    const float* __restrict__ W2, unsigned short* __restrict__ W2Tg) {
    int t = threadIdx.x;
#pragma unroll 4
    for (int i = 0; i < 64; ++i) {
        int idx = i * 256 + t;        // coalesced read
        int h = idx >> 7, n = idx & 127;
        W2Tg[n * 136 + h] = f2bf(W2[idx]);
    }
    for (int idx = t; idx < 1024; idx += 256) {   // zero pad cols 128..135
        int n = idx >> 3, c = 128 + (idx & 7);
        W2Tg[n * 136 + c] = 0;
    }
}

__global__ __launch_bounds__(256) void build_table(
    const float* __restrict__ W1, const float* __restrict__ b1,
    const unsigned short* __restrict__ W2Tg, const float* __restrict__ b2,
    const float* __restrict__ W3, const float* __restrict__ b3,
    float* __restrict__ tabF, float* __restrict__ tabC) {
    __shared__ __attribute__((aligned(16))) float sW1[6 * 128];
    __shared__ __attribute__((aligned(16))) float sb1[128], sb2[128], sW3[128];
    __shared__ __attribute__((aligned(16))) unsigned short sH1[ENTRIES][136];
    __shared__ __attribute__((aligned(16))) unsigned short sW2T[128][136];

    const int t = threadIdx.x;

    // ---- stage weights (W2T is a straight 16B-vector copy) ----
    if (t < 128) { sb1[t] = b1[t]; sb2[t] = b2[t]; sW3[t] = W3[t]; }
    for (int i = t; i < 768; i += 256) sW1[i] = W1[i];
    {
        unsigned short* dst = &sW2T[0][0];
#pragma unroll
        for (int i = 0; i < 8; ++i) {   // 8 x 2048 ushorts
            int off = i * 2048 + t * 8;
            *reinterpret_cast<ushort8_t*>(dst + off) =
                *reinterpret_cast<const ushort8_t*>(W2Tg + off);
        }
        if (t < 128) {                  // tail 1024 ushorts (total 128*136=17408)
            int off = 16384 + t * 8;
            *reinterpret_cast<ushort8_t*>(dst + off) =
                *reinterpret_cast<const ushort8_t*>(W2Tg + off);
        }
    }

    // block -> table segment (wave-uniform)
    int eb = blockIdx.x * ENTRIES;
    float dd; float* tp; int lo;
    if (eb < NFINE) { dd = DFINE;   tp = tabF; lo = eb; }
    else            { dd = DCOARSE; tp = tabC; lo = eb - NFINE; }

    __syncthreads();

    // ---- phase 1: h1 = tanh(feat @ W1 + b1) -> bf16 sH1. 4 entries x 8 cols/thread.
    {
        int e0 = (t >> 4) * 4;
        int c0 = (t & 15) * 8;
        float wf[6][8];
#pragma unroll
        for (int k = 0; k < 6; ++k) {
            *reinterpret_cast<float4*>(&wf[k][0]) = *reinterpret_cast<const float4*>(&sW1[k * 128 + c0]);
            *reinterpret_cast<float4*>(&wf[k][4]) = *reinterpret_cast<const float4*>(&sW1[k * 128 + c0 + 4]);
        }
        float bb[8];
        *reinterpret_cast<float4*>(&bb[0]) = *reinterpret_cast<const float4*>(&sb1[c0]);
        *reinterpret_cast<float4*>(&bb[4]) = *reinterpret_cast<const float4*>(&sb1[c0 + 4]);
#pragma unroll
        for (int ei = 0; ei < 4; ++ei) {
            int e = e0 + ei;
            float d = (float)(lo + e) * dd;
            float inv_r = 1.0f / fmaxf(d, 0.5f);
            float inv2  = inv_r * inv_r;
            float inv6  = inv2 * inv2 * inv2;
            float inv12 = inv6 * inv6;
            float ft[6] = {d, inv_r, inv6, inv12, inv6 * inv_r, inv12 * inv_r};
            float ac[8];
#pragma unroll
            for (int j = 0; j < 8; ++j) ac[j] = bb[j];
#pragma unroll
            for (int k = 0; k < 6; ++k)
#pragma unroll
                for (int j = 0; j < 8; ++j) ac[j] = fmaf(ft[k], wf[k][j], ac[j]);
            ushort8_t pk;
#pragma unroll
            for (int j = 0; j < 8; ++j) pk[j] = f2bf(fast_tanh(ac[j]));
            *reinterpret_cast<ushort8_t*>(&sH1[e][c0]) = pk;
        }
    }
    __syncthreads();

    // ---- phase 2: MFMA layer2 + fused tanh/W3 epilogue ----
    {
        int w  = t >> 6;     // wave -> m-tile rows w*16..w*16+15
        int l  = t & 63;
        int lg = l >> 4;     // k-group
        int lr = l & 15;     // A-row / B-col within tile

        bf16x8 afr[4];
#pragma unroll
        for (int kt = 0; kt < 4; ++kt)
            afr[kt] = *reinterpret_cast<const bf16x8*>(&sH1[w * 16 + lr][kt * 32 + lg * 8]);

        float part[4] = {0.f, 0.f, 0.f, 0.f};
        float b3v = b3[0];
#pragma unroll
        for (int nt = 0; nt < 8; ++nt) {
            f32x4 acc = {0.f, 0.f, 0.f, 0.f};
#pragma unroll
            for (int kt = 0; kt < 4; ++kt) {
                bf16x8 bfr = *reinterpret_cast<const bf16x8*>(&sW2T[nt * 16 + lr][kt * 32 + lg * 8]);
                acc = __builtin_amdgcn_mfma_f32_16x16x32_bf16(afr[kt], bfr, acc, 0, 0, 0);
            }
            float b2v = sb2[nt * 16 + lr];
            float w3v = sW3[nt * 16 + lr];
#pragma unroll
            for (int r = 0; r < 4; ++r)
                part[r] = fmaf(fast_tanh(acc[r] + b2v), w3v, part[r]);
        }
#pragma unroll
        for (int s = 1; s < 16; s <<= 1) {
#pragma unroll
            for (int r = 0; r < 4; ++r) part[r] += __shfl_xor(part[r], s);
        }
        if (lr == 0) {
            int ebase = w * 16 + lg * 4;   // D row = (l>>4)*4 + r
#pragma unroll
            for (int r = 0; r < 4; ++r) {
                int ee = lo + ebase + r;
                float d = (float)ee * dd;
                tp[ee] = (part[r] + b3v) / fmaxf(d, 0.01f);
            }
        }
    }
}

// One wave per (b, i); lane = j. 4 i's per 256-thread block.
__global__ __launch_bounds__(256) void force_kernel(
    const float* __restrict__ pos, const float* __restrict__ tabF,
    const float* __restrict__ tabC, float* __restrict__ out) {
    __shared__ float sp[192];
    int b = blockIdx.x >> 4;
    int igrp = (blockIdx.x & 15) << 2;
    for (int idx = threadIdx.x; idx < 192; idx += 256)
        sp[idx] = pos[b * 192 + idx];
    __syncthreads();

    int w = threadIdx.x >> 6;
    int lane = threadIdx.x & 63;
    int i = igrp + w;

    float xi = sp[i * 3 + 0], yi = sp[i * 3 + 1], zi = sp[i * 3 + 2];
    float dx = xi - sp[lane * 3 + 0];
    float dy = yi - sp[lane * 3 + 1];
    float dz = zi - sp[lane * 3 + 2];
    float sq = fmaf(dx, dx, fmaf(dy, dy, dz * dz));
    float dist = sqrtf(sq);

    bool fine = dist < 2.0f;
    const float* tb = fine ? tabF : tabC;
    float scale = fine ? ((float)NFINE / 2.0f) : ((float)NCOARSE / 16.0f);
    int tmax = fine ? NFINE : NCOARSE;
    float tpos = dist * scale;
    int i0 = (int)tpos;
    i0 = min(i0, tmax - 2);
    float fr = tpos - (float)i0;
    float g0 = tb[i0], g1 = tb[i0 + 1];
    float g = fmaf(fr, g1 - g0, g0);
    if (lane == i) g = 0.0f;   // off-diagonal mask

    float fx = g * dx, fy = g * dy, fz = g * dz;
#pragma unroll
    for (int s = 32; s > 0; s >>= 1) {
        fx += __shfl_xor(fx, s);
        fy += __shfl_xor(fy, s);
        fz += __shfl_xor(fz, s);
    }
    if (lane == 0) {
        int o = (b * 64 + i) * 3;
        out[o + 0] = fx;
        out[o + 1] = fy;
        out[o + 2] = fz;
    }
}

extern "C" void kernel_launch(void* const* d_in, const int* in_sizes, int n_in,
                              void* d_out, int out_size, void* d_ws, size_t ws_size,
                              hipStream_t stream) {
    const float* pos = (const float*)d_in[0];
    const float* W1  = (const float*)d_in[1];
    const float* b1  = (const float*)d_in[2];
    const float* W2  = (const float*)d_in[3];
    const float* b2  = (const float*)d_in[4];
    const float* W3  = (const float*)d_in[5];
    const float* b3  = (const float*)d_in[6];

    char* ws = (char*)d_ws;
    float* tabF = (float*)(ws);                               // 256 KiB
    float* tabC = (float*)(ws + (size_t)NFINE * 4);           // 64 KiB
    unsigned short* W2Tg = (unsigned short*)(ws + (size_t)(NFINE + NCOARSE) * 4);  // 34816 B
    float* out = (float*)d_out;

    hipLaunchKernelGGL(prep_w2, dim3(1), dim3(256), 0, stream, W2, W2Tg);
    hipLaunchKernelGGL(build_table, dim3((NFINE + NCOARSE) / ENTRIES), dim3(256), 0, stream,
                       W1, b1, W2Tg, b2, W3, b3, tabF, tabC);
    hipLaunchKernelGGL(force_kernel, dim3(512 * 16), dim3(256), 0, stream,
                       pos, tabF, tabC, out);
}

// Round 4
// 26.997 us; speedup vs baseline: 4.0497x; 1.4649x over previous
//
#include <hip/hip_runtime.h>
#include <hip/hip_bf16.h>
#include <math.h>

// Problem: B=512, N=64, D=3, H=128.
// out[b,i,:] = sum_{j != i} g(dist_ij) * (pos[b,i,:] - pos[b,j,:])
// where g(d) = (MLP(features(d)) + b3) / max(d, 0.01).
// g depends ONLY on scalar dist -> tabulate g, lerp.
// Fine table [0,2) x 32768 (tanh-front), coarse [0,16) x 8192.
// Layer2 is [E,128]@[128,128] -> bf16 MFMA; A-frags built directly in regs.

#define NFINE   32768
#define NCOARSE 8192
#define ENTRIES 64

typedef __attribute__((ext_vector_type(8))) short bf16x8;
typedef __attribute__((ext_vector_type(4))) float f32x4;
typedef __attribute__((ext_vector_type(8))) unsigned short ushort8_t;

__device__ __forceinline__ float fast_tanh(float x) {
    float e = __expf(2.0f * x);
    return 1.0f - 2.0f * __builtin_amdgcn_rcpf(e + 1.0f);
}

__device__ __forceinline__ unsigned short f2bf(float x) {
    __hip_bfloat16 h = __float2bfloat16(x);
    return *reinterpret_cast<unsigned short*>(&h);
}

// One-time: W2 [128h][128n] fp32 -> W2T [n][h] bf16 (rows padded to 136).
// 128 blocks (one per n) x 64 lanes: coalesced ushort2 writes, scattered
// reads spread across CUs (L2-resident 64 KB).
__global__ __launch_bounds__(64) void prep_w2(
    const float* __restrict__ W2, unsigned short* __restrict__ W2Tg) {
    int n = blockIdx.x, l = threadIdx.x;
    float a = W2[(2 * l) * 128 + n];
    float b = W2[(2 * l + 1) * 128 + n];
    *reinterpret_cast<ushort2*>(&W2Tg[n * 136 + 2 * l]) =
        make_ushort2(f2bf(a), f2bf(b));
    if (l < 4)
        *reinterpret_cast<ushort2*>(&W2Tg[n * 136 + 128 + 2 * l]) = make_ushort2(0, 0);
}

__global__ __launch_bounds__(256) void build_table(
    const float* __restrict__ W1, const float* __restrict__ b1,
    const unsigned short* __restrict__ W2Tg, const float* __restrict__ b2,
    const float* __restrict__ W3, const float* __restrict__ b3,
    float* __restrict__ tabF, float* __restrict__ tabC) {
    __shared__ __attribute__((aligned(16))) float sW1[6 * 128];
    __shared__ __attribute__((aligned(16))) float sb1[128], sb2[128], sW3[128];
    __shared__ __attribute__((aligned(16))) unsigned short sW2T[128][136];  // 34816 B

    const int t = threadIdx.x;

    // ---- stage weights (W2T is a straight 16B-vector copy) ----
    if (t < 128) { sb1[t] = b1[t]; sb2[t] = b2[t]; sW3[t] = W3[t]; }
    for (int i = t; i < 768; i += 256) sW1[i] = W1[i];
    {
        unsigned short* dst = &sW2T[0][0];
#pragma unroll
        for (int i = 0; i < 8; ++i) {   // 8 x 2048 ushorts
            int off = i * 2048 + t * 8;
            *reinterpret_cast<ushort8_t*>(dst + off) =
                *reinterpret_cast<const ushort8_t*>(W2Tg + off);
        }
        if (t < 128) {                  // tail (total 128*136=17408)
            int off = 16384 + t * 8;
            *reinterpret_cast<ushort8_t*>(dst + off) =
                *reinterpret_cast<const ushort8_t*>(W2Tg + off);
        }
    }

    // block -> table segment (wave-uniform)
    int eb = blockIdx.x * ENTRIES;
    float dd; float* tp; int lo;
    if (eb < NFINE) { dd = 2.0f / (float)NFINE;   tp = tabF; lo = eb; }
    else            { dd = 16.0f / (float)NCOARSE; tp = tabC; lo = eb - NFINE; }

    const int w  = t >> 6;    // wave -> m-tile rows w*16..w*16+15
    const int l  = t & 63;
    const int lg = l >> 4;    // k-group
    const int lr = l & 15;    // A-row / B-col within tile

    // thread's table entry (== its A-fragment row)
    const int e = w * 16 + lr;
    float d = (float)(lo + e) * dd;
    float inv_r = 1.0f / fmaxf(d, 0.5f);
    float inv2  = inv_r * inv_r;
    float inv6  = inv2 * inv2 * inv2;
    float inv12 = inv6 * inv6;
    float ft[6] = {d, inv_r, inv6, inv12, inv6 * inv_r, inv12 * inv_r};

    __syncthreads();

    // ---- phase 1: layer-1 for exactly this thread's A-frag elements ----
    // A-frag (16x16x32): lane holds row lr, k = kt*32 + lg*8 + j.
    bf16x8 afr[4];
#pragma unroll
    for (int kt = 0; kt < 4; ++kt) {
        int c0 = kt * 32 + lg * 8;
        float ac[8], wv[8];
        *reinterpret_cast<float4*>(&ac[0]) = *reinterpret_cast<const float4*>(&sb1[c0]);
        *reinterpret_cast<float4*>(&ac[4]) = *reinterpret_cast<const float4*>(&sb1[c0 + 4]);
#pragma unroll
        for (int k = 0; k < 6; ++k) {
            *reinterpret_cast<float4*>(&wv[0]) = *reinterpret_cast<const float4*>(&sW1[k * 128 + c0]);
            *reinterpret_cast<float4*>(&wv[4]) = *reinterpret_cast<const float4*>(&sW1[k * 128 + c0 + 4]);
#pragma unroll
            for (int j = 0; j < 8; ++j) ac[j] = fmaf(ft[k], wv[j], ac[j]);
        }
        ushort8_t pk;
#pragma unroll
        for (int j = 0; j < 8; ++j) pk[j] = f2bf(fast_tanh(ac[j]));
        afr[kt] = *reinterpret_cast<bf16x8*>(&pk);
    }

    // ---- phase 2: MFMA layer2 + fused tanh/W3 epilogue ----
    {
        float part[4] = {0.f, 0.f, 0.f, 0.f};
        float b3v = b3[0];
#pragma unroll
        for (int nt = 0; nt < 8; ++nt) {
            f32x4 acc = {0.f, 0.f, 0.f, 0.f};
#pragma unroll
            for (int kt = 0; kt < 4; ++kt) {
                bf16x8 bfr = *reinterpret_cast<const bf16x8*>(&sW2T[nt * 16 + lr][kt * 32 + lg * 8]);
                acc = __builtin_amdgcn_mfma_f32_16x16x32_bf16(afr[kt], bfr, acc, 0, 0, 0);
            }
            float b2v = sb2[nt * 16 + lr];
            float w3v = sW3[nt * 16 + lr];
#pragma unroll
            for (int r = 0; r < 4; ++r)
                part[r] = fmaf(fast_tanh(acc[r] + b2v), w3v, part[r]);
        }
#pragma unroll
        for (int s = 1; s < 16; s <<= 1) {
#pragma unroll
            for (int r = 0; r < 4; ++r) part[r] += __shfl_xor(part[r], s);
        }
        if (lr == 0) {
            int ebase = w * 16 + lg * 4;   // D row = (l>>4)*4 + r
#pragma unroll
            for (int r = 0; r < 4; ++r) {
                int ee = lo + ebase + r;
                float dr = (float)ee * dd;
                tp[ee] = (part[r] + b3v) / fmaxf(dr, 0.01f);
            }
        }
    }
}

// One wave per (b, i); lane = j. 4 i's per 256-thread block.
__global__ __launch_bounds__(256) void force_kernel(
    const float* __restrict__ pos, const float* __restrict__ tabF,
    const float* __restrict__ tabC, float* __restrict__ out) {
    __shared__ float sp[192];
    int b = blockIdx.x >> 4;
    int igrp = (blockIdx.x & 15) << 2;
    for (int idx = threadIdx.x; idx < 192; idx += 256)
        sp[idx] = pos[b * 192 + idx];
    __syncthreads();

    int w = threadIdx.x >> 6;
    int lane = threadIdx.x & 63;
    int i = igrp + w;

    float xi = sp[i * 3 + 0], yi = sp[i * 3 + 1], zi = sp[i * 3 + 2];
    float dx = xi - sp[lane * 3 + 0];
    float dy = yi - sp[lane * 3 + 1];
    float dz = zi - sp[lane * 3 + 2];
    float sq = fmaf(dx, dx, fmaf(dy, dy, dz * dz));
    float dist = sqrtf(sq);

    bool fine = dist < 2.0f;
    const float* tb = fine ? tabF : tabC;
    float scale = fine ? ((float)NFINE / 2.0f) : ((float)NCOARSE / 16.0f);
    int tmax = fine ? NFINE : NCOARSE;
    float tpos = dist * scale;
    int i0 = (int)tpos;
    i0 = min(i0, tmax - 2);
    float fr = tpos - (float)i0;
    float g0 = tb[i0], g1 = tb[i0 + 1];
    float g = fmaf(fr, g1 - g0, g0);
    if (lane == i) g = 0.0f;   // off-diagonal mask

    float fx = g * dx, fy = g * dy, fz = g * dz;
#pragma unroll
    for (int s = 32; s > 0; s >>= 1) {
        fx += __shfl_xor(fx, s);
        fy += __shfl_xor(fy, s);
        fz += __shfl_xor(fz, s);
    }
    if (lane == 0) {
        int o = (b * 64 + i) * 3;
        out[o + 0] = fx;
        out[o + 1] = fy;
        out[o + 2] = fz;
    }
}

extern "C" void kernel_launch(void* const* d_in, const int* in_sizes, int n_in,
                              void* d_out, int out_size, void* d_ws, size_t ws_size,
                              hipStream_t stream) {
    const float* pos = (const float*)d_in[0];
    const float* W1  = (const float*)d_in[1];
    const float* b1  = (const float*)d_in[2];
    const float* W2  = (const float*)d_in[3];
    const float* b2  = (const float*)d_in[4];
    const float* W3  = (const float*)d_in[5];
    const float* b3  = (const float*)d_in[6];

    char* ws = (char*)d_ws;
    float* tabF = (float*)(ws);                               // 128 KiB
    float* tabC = (float*)(ws + (size_t)NFINE * 4);           // 32 KiB
    unsigned short* W2Tg = (unsigned short*)(ws + (size_t)(NFINE + NCOARSE) * 4);  // 34816 B
    float* out = (float*)d_out;

    hipLaunchKernelGGL(prep_w2, dim3(128), dim3(64), 0, stream, W2, W2Tg);
    hipLaunchKernelGGL(build_table, dim3((NFINE + NCOARSE) / ENTRIES), dim3(256), 0, stream,
                       W1, b1, W2Tg, b2, W3, b3, tabF, tabC);
    hipLaunchKernelGGL(force_kernel, dim3(512 * 16), dim3(256), 0, stream,
                       pos, tabF, tabC, out);
}

// Round 5
// 23.490 us; speedup vs baseline: 4.6543x; 1.1493x over previous
//
#include <hip/hip_runtime.h>
#include <hip/hip_bf16.h>
#include <math.h>

// Problem: B=512, N=64, D=3, H=128.
// out[b,i,:] = sum_{j != i} g(dist_ij) * (pos[b,i,:] - pos[b,j,:])
// where g(d) = (MLP(features(d)) + b3) / max(d, 0.01).
// g depends ONLY on scalar dist -> tabulate g, lerp.
// Fine table [0,2) x 32768 (tanh-front), coarse [0,16) x 8192.
// Layer2 is [E,128]@[128,128] -> bf16 MFMA; A-frags built directly in regs.
// Force: one block per batch, 16 (i,j) pairs per thread.

#define NFINE   32768
#define NCOARSE 8192
#define ENTRIES 64

typedef __attribute__((ext_vector_type(8))) short bf16x8;
typedef __attribute__((ext_vector_type(4))) float f32x4;
typedef __attribute__((ext_vector_type(8))) unsigned short ushort8_t;

__device__ __forceinline__ float fast_tanh(float x) {
    float e = __expf(2.0f * x);
    return 1.0f - 2.0f * __builtin_amdgcn_rcpf(e + 1.0f);
}

__device__ __forceinline__ unsigned short f2bf(float x) {
    __hip_bfloat16 h = __float2bfloat16(x);
    return *reinterpret_cast<unsigned short*>(&h);
}

// One-time: W2 [128h][128n] fp32 -> W2T [n][h] bf16 (rows padded to 136).
// 128 blocks (one per n) x 64 lanes: coalesced ushort2 writes.
__global__ __launch_bounds__(64) void prep_w2(
    const float* __restrict__ W2, unsigned short* __restrict__ W2Tg) {
    int n = blockIdx.x, l = threadIdx.x;
    float a = W2[(2 * l) * 128 + n];
    float b = W2[(2 * l + 1) * 128 + n];
    *reinterpret_cast<ushort2*>(&W2Tg[n * 136 + 2 * l]) =
        make_ushort2(f2bf(a), f2bf(b));
    if (l < 4)
        *reinterpret_cast<ushort2*>(&W2Tg[n * 136 + 128 + 2 * l]) = make_ushort2(0, 0);
}

__global__ __launch_bounds__(256) void build_table(
    const float* __restrict__ W1, const float* __restrict__ b1,
    const unsigned short* __restrict__ W2Tg, const float* __restrict__ b2,
    const float* __restrict__ W3, const float* __restrict__ b3,
    float* __restrict__ tabF, float* __restrict__ tabC) {
    __shared__ __attribute__((aligned(16))) float sW1[6 * 128];
    __shared__ __attribute__((aligned(16))) float sb1[128], sb2[128], sW3[128];
    __shared__ __attribute__((aligned(16))) unsigned short sW2T[128][136];  // 34816 B

    const int t = threadIdx.x;

    // ---- stage weights (W2T is a straight 16B-vector copy) ----
    if (t < 128) { sb1[t] = b1[t]; sb2[t] = b2[t]; sW3[t] = W3[t]; }
    for (int i = t; i < 768; i += 256) sW1[i] = W1[i];
    {
        unsigned short* dst = &sW2T[0][0];
#pragma unroll
        for (int i = 0; i < 8; ++i) {   // 8 x 2048 ushorts
            int off = i * 2048 + t * 8;
            *reinterpret_cast<ushort8_t*>(dst + off) =
                *reinterpret_cast<const ushort8_t*>(W2Tg + off);
        }
        if (t < 128) {                  // tail (total 128*136=17408)
            int off = 16384 + t * 8;
            *reinterpret_cast<ushort8_t*>(dst + off) =
                *reinterpret_cast<const ushort8_t*>(W2Tg + off);
        }
    }

    // block -> table segment (wave-uniform)
    int eb = blockIdx.x * ENTRIES;
    float dd; float* tp; int lo;
    if (eb < NFINE) { dd = 2.0f / (float)NFINE;   tp = tabF; lo = eb; }
    else            { dd = 16.0f / (float)NCOARSE; tp = tabC; lo = eb - NFINE; }

    const int w  = t >> 6;    // wave -> m-tile rows w*16..w*16+15
    const int l  = t & 63;
    const int lg = l >> 4;    // k-group
    const int lr = l & 15;    // A-row / B-col within tile

    // thread's table entry (== its A-fragment row)
    const int e = w * 16 + lr;
    float d = (float)(lo + e) * dd;
    float inv_r = 1.0f / fmaxf(d, 0.5f);
    float inv2  = inv_r * inv_r;
    float inv6  = inv2 * inv2 * inv2;
    float inv12 = inv6 * inv6;
    float ft[6] = {d, inv_r, inv6, inv12, inv6 * inv_r, inv12 * inv_r};

    __syncthreads();

    // ---- phase 1: layer-1 for exactly this thread's A-frag elements ----
    // A-frag (16x16x32): lane holds row lr, k = kt*32 + lg*8 + j.
    bf16x8 afr[4];
#pragma unroll
    for (int kt = 0; kt < 4; ++kt) {
        int c0 = kt * 32 + lg * 8;
        float ac[8], wv[8];
        *reinterpret_cast<float4*>(&ac[0]) = *reinterpret_cast<const float4*>(&sb1[c0]);
        *reinterpret_cast<float4*>(&ac[4]) = *reinterpret_cast<const float4*>(&sb1[c0 + 4]);
#pragma unroll
        for (int k = 0; k < 6; ++k) {
            *reinterpret_cast<float4*>(&wv[0]) = *reinterpret_cast<const float4*>(&sW1[k * 128 + c0]);
            *reinterpret_cast<float4*>(&wv[4]) = *reinterpret_cast<const float4*>(&sW1[k * 128 + c0 + 4]);
#pragma unroll
            for (int j = 0; j < 8; ++j) ac[j] = fmaf(ft[k], wv[j], ac[j]);
        }
        ushort8_t pk;
#pragma unroll
        for (int j = 0; j < 8; ++j) pk[j] = f2bf(fast_tanh(ac[j]));
        afr[kt] = *reinterpret_cast<bf16x8*>(&pk);
    }

    // ---- phase 2: MFMA layer2 + fused tanh/W3 epilogue ----
    {
        float part[4] = {0.f, 0.f, 0.f, 0.f};
        float b3v = b3[0];
#pragma unroll
        for (int nt = 0; nt < 8; ++nt) {
            f32x4 acc = {0.f, 0.f, 0.f, 0.f};
#pragma unroll
            for (int kt = 0; kt < 4; ++kt) {
                bf16x8 bfr = *reinterpret_cast<const bf16x8*>(&sW2T[nt * 16 + lr][kt * 32 + lg * 8]);
                acc = __builtin_amdgcn_mfma_f32_16x16x32_bf16(afr[kt], bfr, acc, 0, 0, 0);
            }
            float b2v = sb2[nt * 16 + lr];
            float w3v = sW3[nt * 16 + lr];
#pragma unroll
            for (int r = 0; r < 4; ++r)
                part[r] = fmaf(fast_tanh(acc[r] + b2v), w3v, part[r]);
        }
#pragma unroll
        for (int s = 1; s < 16; s <<= 1) {
#pragma unroll
            for (int r = 0; r < 4; ++r) part[r] += __shfl_xor(part[r], s);
        }
        if (lr == 0) {
            int ebase = w * 16 + lg * 4;   // D row = (l>>4)*4 + r
#pragma unroll
            for (int r = 0; r < 4; ++r) {
                int ee = lo + ebase + r;
                float dr = (float)ee * dd;
                tp[ee] = (part[r] + b3v) / fmaxf(dr, 0.01f);
            }
        }
    }
}

// One block per batch b. Thread t: i = t>>2, j in [16*(t&3), 16*(t&3)+16).
__global__ __launch_bounds__(256) void force_kernel(
    const float* __restrict__ pos, const float* __restrict__ tabF,
    const float* __restrict__ tabC, float* __restrict__ out) {
    __shared__ float sp[192];
    int b = blockIdx.x;
    int t = threadIdx.x;
    if (t < 192) sp[t] = pos[b * 192 + t];
    __syncthreads();

    int i  = t >> 2;
    int j0 = (t & 3) * 16;
    float xi = sp[i * 3 + 0], yi = sp[i * 3 + 1], zi = sp[i * 3 + 2];
    float fx = 0.f, fy = 0.f, fz = 0.f;
#pragma unroll
    for (int jj = 0; jj < 16; ++jj) {
        int j = j0 + jj;
        float dx = xi - sp[j * 3 + 0];
        float dy = yi - sp[j * 3 + 1];
        float dz = zi - sp[j * 3 + 2];
        float sq = fmaf(dx, dx, fmaf(dy, dy, dz * dz));
        float dist = sqrtf(sq);

        bool fine = dist < 2.0f;
        const float* tb = fine ? tabF : tabC;
        float scale = fine ? ((float)NFINE / 2.0f) : ((float)NCOARSE / 16.0f);
        int tmax = fine ? NFINE : NCOARSE;
        float tpos = dist * scale;
        int i0 = min((int)tpos, tmax - 2);
        float fr = tpos - (float)i0;
        float g0 = tb[i0], g1 = tb[i0 + 1];
        float g = fmaf(fr, g1 - g0, g0);
        if (j == i) g = 0.0f;   // off-diagonal mask

        fx = fmaf(g, dx, fx);
        fy = fmaf(g, dy, fy);
        fz = fmaf(g, dz, fz);
    }
    // reduce the 4 j-quarters (lanes t, t^1, t^2 within the aligned 4-group)
    fx += __shfl_xor(fx, 1); fy += __shfl_xor(fy, 1); fz += __shfl_xor(fz, 1);
    fx += __shfl_xor(fx, 2); fy += __shfl_xor(fy, 2); fz += __shfl_xor(fz, 2);
    if ((t & 3) == 0) {
        int o = (b * 64 + i) * 3;
        out[o + 0] = fx;
        out[o + 1] = fy;
        out[o + 2] = fz;
    }
}

extern "C" void kernel_launch(void* const* d_in, const int* in_sizes, int n_in,
                              void* d_out, int out_size, void* d_ws, size_t ws_size,
                              hipStream_t stream) {
    const float* pos = (const float*)d_in[0];
    const float* W1  = (const float*)d_in[1];
    const float* b1  = (const float*)d_in[2];
    const float* W2  = (const float*)d_in[3];
    const float* b2  = (const float*)d_in[4];
    const float* W3  = (const float*)d_in[5];
    const float* b3  = (const float*)d_in[6];

    char* ws = (char*)d_ws;
    float* tabF = (float*)(ws);                               // 128 KiB
    float* tabC = (float*)(ws + (size_t)NFINE * 4);           // 32 KiB
    unsigned short* W2Tg = (unsigned short*)(ws + (size_t)(NFINE + NCOARSE) * 4);  // 34816 B
    float* out = (float*)d_out;

    hipLaunchKernelGGL(prep_w2, dim3(128), dim3(64), 0, stream, W2, W2Tg);
    hipLaunchKernelGGL(build_table, dim3((NFINE + NCOARSE) / ENTRIES), dim3(256), 0, stream,
                       W1, b1, W2Tg, b2, W3, b3, tabF, tabC);
    hipLaunchKernelGGL(force_kernel, dim3(512), dim3(256), 0, stream,
                       pos, tabF, tabC, out);
}